// Round 2
// baseline (312.754 us; speedup 1.0000x reference)
//
#include <hip/hip_runtime.h>
#include <hip/hip_bf16.h>

// Problem: B=4, N=M=2048, D=512, H=8, HS=64, OUT=512
// Pipeline:
//   conv_wqkv : [H][D][HS] fp32 -> Wt[h*64+hs][k] bf16 (q scaled by 1/8)
//   conv_wp   : [H][HS][OUT] fp32 -> Wt[out][h*64+hs] bf16
//   gemm128<0>: X fp32 [8192,512] x Wt -> Q/K/V bf16 [B][H][n][64]
//   attn64    : flash attention per (b,h), 64 q-rows/block -> MH bf16 [B][N][512]
//   gemm128<1>: MH x Wp_t + bias -> out fp32 [8192,512]

typedef __attribute__((ext_vector_type(8))) short short8;
typedef __attribute__((ext_vector_type(4))) float f32x4;

#define MFMA16(a, b, c) __builtin_amdgcn_mfma_f32_16x16x32_bf16(a, b, c, 0, 0, 0)

__device__ __forceinline__ short f2bf(float f) {
  unsigned u = __builtin_bit_cast(unsigned, f);
  u += 0x7FFF + ((u >> 16) & 1);   // RNE
  return (short)(u >> 16);
}

// XOR swizzle for 128B-row LDS tiles: spread rows across bank groups.
__device__ __forceinline__ unsigned swz(unsigned byte) {
  return byte ^ (((byte >> 7) & 7) << 4);
}

// ---------------- weight conversion ----------------

__global__ void conv_wqkv(const float* __restrict__ Wq, const float* __restrict__ Wk,
                          const float* __restrict__ Wv,
                          short* __restrict__ Oq, short* __restrict__ Ok,
                          short* __restrict__ Ov) {
  int z = blockIdx.y;
  const float* W = (z == 0) ? Wq : (z == 1) ? Wk : Wv;
  short* O = (z == 0) ? Oq : (z == 1) ? Ok : Ov;
  float scale = (z == 0) ? 0.125f : 1.0f;   // q / sqrt(HS), exact pow2
  int tid = blockIdx.x * 256 + threadIdx.x;        // 0..262143
  int n = tid >> 9, k = tid & 511;                 // out[n][k]
  int h = n >> 6, hs = n & 63;
  O[tid] = f2bf(W[(h * 512 + k) * 64 + hs] * scale);
}

__global__ void conv_wp(const float* __restrict__ W, short* __restrict__ O) {
  int tid = blockIdx.x * 256 + threadIdx.x;
  int n = tid >> 9, k = tid & 511;                 // out[n][k] = in[k][n]
  O[tid] = f2bf(W[k * 512 + n]);
}

// ---------------- GEMM: 128x128 tile, BK=64, 4 waves (2x2), 16x16x32 bf16 ----------------
// MODE 0: A fp32 (converted on stage), epilogue scatter to [B][H][n][hs] bf16
// MODE 1: A bf16, epilogue fp32 + bias to [row][col]

template <int MODE>
__global__ __launch_bounds__(256) void gemm128(
    const void* __restrict__ A0, const void* __restrict__ A1, const void* __restrict__ A2,
    const short* __restrict__ B0, const short* __restrict__ B1, const short* __restrict__ B2,
    void* __restrict__ O0, void* __restrict__ O1, void* __restrict__ O2,
    const float* __restrict__ bias) {
  __shared__ alignas(16) char lds[32768];  // A tile 16KB @0, B tile 16KB @16384
  const int z = blockIdx.z;
  const void* Ap = (z == 0) ? A0 : (z == 1) ? A1 : A2;
  const short* Bp = (z == 0) ? B0 : (z == 1) ? B1 : B2;
  void* Op = (z == 0) ? O0 : (z == 1) ? O1 : O2;

  const int tid = threadIdx.x;
  const int r0 = blockIdx.x * 128;
  const int n0 = blockIdx.y * 128;
  const int wid = tid >> 6, lane = tid & 63, g = lane >> 4, c = lane & 15;
  const int wr = wid >> 1, wc = wid & 1;

  f32x4 acc[4][4] = {};

  for (int ks = 0; ks < 8; ++ks) {
    const int k0 = ks * 64;
    if (ks) __syncthreads();
    // ---- stage A[128][64] and B[128][64] (B = Wt rows = n) ----
#pragma unroll
    for (int it = 0; it < 4; ++it) {
      int e = tid + 256 * it;         // 0..1023
      int row = e >> 3, c8 = e & 7;   // 128 rows x 8 chunks of 8 elems
      short8 s;
      if (MODE == 0) {
        const float* src = (const float*)Ap + (size_t)(r0 + row) * 512 + k0 + c8 * 8;
        float4 fa = *(const float4*)(src);
        float4 fb = *(const float4*)(src + 4);
        s[0] = f2bf(fa.x); s[1] = f2bf(fa.y); s[2] = f2bf(fa.z); s[3] = f2bf(fa.w);
        s[4] = f2bf(fb.x); s[5] = f2bf(fb.y); s[6] = f2bf(fb.z); s[7] = f2bf(fb.w);
      } else {
        s = *(const short8*)((const short*)Ap + (size_t)(r0 + row) * 512 + k0 + c8 * 8);
      }
      *(short8*)(lds + swz(row * 128 + c8 * 16)) = s;
      short8 bs = *(const short8*)(Bp + (size_t)(n0 + row) * 512 + k0 + c8 * 8);
      *(short8*)(lds + swz(16384 + row * 128 + c8 * 16)) = bs;
    }
    __syncthreads();
    // ---- fragments + MFMA ----
    short8 af[4][2], bf[4][2];
#pragma unroll
    for (int mt = 0; mt < 4; ++mt)
#pragma unroll
      for (int kk = 0; kk < 2; ++kk) {
        int row = wr * 64 + mt * 16 + c;
        af[mt][kk] = *(const short8*)(lds + swz(row * 128 + (g + 4 * kk) * 16));
      }
#pragma unroll
    for (int nt = 0; nt < 4; ++nt)
#pragma unroll
      for (int kk = 0; kk < 2; ++kk) {
        int nr = wc * 64 + nt * 16 + c;
        bf[nt][kk] = *(const short8*)(lds + swz(16384 + nr * 128 + (g + 4 * kk) * 16));
      }
#pragma unroll
    for (int mt = 0; mt < 4; ++mt)
#pragma unroll
      for (int nt = 0; nt < 4; ++nt) {
        acc[mt][nt] = MFMA16(af[mt][0], bf[nt][0], acc[mt][nt]);
        acc[mt][nt] = MFMA16(af[mt][1], bf[nt][1], acc[mt][nt]);
      }
  }

  // ---- epilogue ----
  if (MODE == 0) {
    short* Ob = (short*)Op;   // [B*H][2048][64], row=b*2048+n, col=h*64+hs
#pragma unroll
    for (int mt = 0; mt < 4; ++mt) {
      int rowb = r0 + wr * 64 + mt * 16 + g * 4;
#pragma unroll
      for (int nt = 0; nt < 4; ++nt) {
        int col = n0 + wc * 64 + nt * 16 + c;
        int h = col >> 6, hs = col & 63;
#pragma unroll
        for (int r = 0; r < 4; ++r) {
          int row = rowb + r;
          int b = row >> 11, nn = row & 2047;
          Ob[(((size_t)(b * 8 + h)) * 2048 + nn) * 64 + hs] = f2bf(acc[mt][nt][r]);
        }
      }
    }
  } else {
    float* Of = (float*)Op;
#pragma unroll
    for (int nt = 0; nt < 4; ++nt) {
      int col = n0 + wc * 64 + nt * 16 + c;
      float bv = bias[col];
#pragma unroll
      for (int mt = 0; mt < 4; ++mt) {
        int rowb = r0 + wr * 64 + mt * 16 + g * 4;
#pragma unroll
        for (int r = 0; r < 4; ++r)
          Of[(size_t)(rowb + r) * 512 + col] = acc[mt][nt][r] + bv;
      }
    }
  }
}

// ---------------- flash attention ----------------
// block = 256 threads = 4 waves; each wave owns 16 q-rows (block: 64 q-rows of one (b,h)).
// LDS: K tile [64][64] bf16 swz @0 (8KB), V^T tile [64 hs][64 kv] swz @8192 (8KB),
//      P per wave [16 q][64 kv] swz @16384 + wid*2048 (4x2KB). Total 24KB.

__global__ __launch_bounds__(256) void attn64(const short* __restrict__ Qb,
                                              const short* __restrict__ Kb,
                                              const short* __restrict__ Vb,
                                              short* __restrict__ MH) {
  __shared__ alignas(16) char lds[24576];
  const int qt = blockIdx.x, h = blockIdx.y, b = blockIdx.z;
  const int bh = b * 8 + h;
  const int tid = threadIdx.x, wid = tid >> 6, lane = tid & 63, g = lane >> 4, c = lane & 15;
  const short* Qp = Qb + ((size_t)bh * 2048 + qt * 64) * 64;
  const short* Kp = Kb + (size_t)bh * 2048 * 64;
  const short* Vp = Vb + (size_t)bh * 2048 * 64;

  // Q fragments: wave's 16 rows, K-dim 64 = 2 chunks of 32
  short8 qf[2];
#pragma unroll
  for (int kk = 0; kk < 2; ++kk)
    qf[kk] = *(const short8*)(Qp + (wid * 16 + c) * 64 + g * 8 + kk * 32);

  f32x4 o[4] = {};
  float mrow[4], lrow[4];
#pragma unroll
  for (int r = 0; r < 4; ++r) { mrow[r] = -1e30f; lrow[r] = 0.f; }

  const int pbase = 16384 + wid * 2048;

  for (int kvt = 0; kvt < 32; ++kvt) {
    __syncthreads();
    // ---- stage K row-major, V transposed ----
#pragma unroll
    for (int it = 0; it < 2; ++it) {
      int e = tid + 256 * it;
      int kv = e >> 3, c8 = e & 7;
      const size_t gidx = (size_t)(kvt * 64 + kv) * 64 + c8 * 8;
      short8 kvec = *(const short8*)(Kp + gidx);
      *(short8*)(lds + swz(kv * 128 + c8 * 16)) = kvec;
      short8 vvec = *(const short8*)(Vp + gidx);
#pragma unroll
      for (int i = 0; i < 8; ++i)
        *(short*)(lds + swz(8192 + (c8 * 8 + i) * 128 + kv * 2)) = vvec[i];
    }
    __syncthreads();

    // ---- S = Q K^T (16 q-rows x 64 kv) ----
    f32x4 s[4] = {};
#pragma unroll
    for (int t = 0; t < 4; ++t)
#pragma unroll
      for (int kk = 0; kk < 2; ++kk) {
        short8 kf = *(const short8*)(lds + swz((t * 16 + c) * 128 + (g + 4 * kk) * 16));
        s[t] = MFMA16(qf[kk], kf, s[t]);
      }

    // ---- online softmax (row r lives at q = g*4+r; kv across 16 lanes x 4 tiles) ----
#pragma unroll
    for (int r = 0; r < 4; ++r) {
      float vm = fmaxf(fmaxf(s[0][r], s[1][r]), fmaxf(s[2][r], s[3][r]));
      vm = fmaxf(vm, __shfl_xor(vm, 1));
      vm = fmaxf(vm, __shfl_xor(vm, 2));
      vm = fmaxf(vm, __shfl_xor(vm, 4));
      vm = fmaxf(vm, __shfl_xor(vm, 8));
      float mn = fmaxf(mrow[r], vm);
      float sc = __expf(mrow[r] - mn);
      float rs = 0.f;
#pragma unroll
      for (int t = 0; t < 4; ++t) {
        float p = __expf(s[t][r] - mn);
        s[t][r] = p;
        rs += p;
      }
      rs += __shfl_xor(rs, 1);
      rs += __shfl_xor(rs, 2);
      rs += __shfl_xor(rs, 4);
      rs += __shfl_xor(rs, 8);
      lrow[r] = lrow[r] * sc + rs;
      mrow[r] = mn;
#pragma unroll
      for (int t = 0; t < 4; ++t) o[t][r] *= sc;
    }

    // ---- P -> LDS (per-wave region, bf16), then PV ----
#pragma unroll
    for (int t = 0; t < 4; ++t)
#pragma unroll
      for (int r = 0; r < 4; ++r)
        *(short*)(lds + swz(pbase + (g * 4 + r) * 128 + (t * 16 + c) * 2)) = f2bf(s[t][r]);
    asm volatile("s_waitcnt lgkmcnt(0)" ::: "memory");

    short8 pa[2];
#pragma unroll
    for (int half = 0; half < 2; ++half)
      pa[half] = *(const short8*)(lds + swz(pbase + c * 128 + (g + 4 * half) * 16));
#pragma unroll
    for (int t = 0; t < 4; ++t)
#pragma unroll
      for (int half = 0; half < 2; ++half) {
        short8 vf = *(const short8*)(lds + swz(8192 + (t * 16 + c) * 128 + (g + 4 * half) * 16));
        o[t] = MFMA16(pa[half], vf, o[t]);
      }
  }

  // ---- epilogue: normalize, write MH[b][n][h*64+hs] bf16 ----
#pragma unroll
  for (int t = 0; t < 4; ++t)
#pragma unroll
    for (int r = 0; r < 4; ++r) {
      float val = o[t][r] / lrow[r];
      int qrow = qt * 64 + wid * 16 + g * 4 + r;
      int col = h * 64 + t * 16 + c;
      MH[((size_t)b * 2048 + qrow) * 512 + col] = f2bf(val);
    }
}

// ---------------- launcher ----------------

extern "C" void kernel_launch(void* const* d_in, const int* in_sizes, int n_in,
                              void* d_out, int out_size, void* d_ws, size_t ws_size,
                              hipStream_t stream) {
  const float* query = (const float*)d_in[0];
  const float* key = (const float*)d_in[1];
  const float* value = (const float*)d_in[2];
  const float* wq = (const float*)d_in[3];
  const float* wk = (const float*)d_in[4];
  const float* wv = (const float*)d_in[5];
  const float* wp = (const float*)d_in[6];
  const float* bias = (const float*)d_in[7];

  char* ws = (char*)d_ws;
  short* Wq_t = (short*)(ws + 0);
  short* Wk_t = (short*)(ws + 524288);
  short* Wv_t = (short*)(ws + 1048576);
  short* Wp_t = (short*)(ws + 1572864);
  short* Qb = (short*)(ws + 2097152);
  short* Kb = (short*)(ws + 2097152 + 8388608);
  short* Vb = (short*)(ws + 2097152 + 2 * (size_t)8388608);
  short* MH = (short*)(ws + 2097152 + 3 * (size_t)8388608);

  conv_wqkv<<<dim3(1024, 3), 256, 0, stream>>>(wq, wk, wv, Wq_t, Wk_t, Wv_t);
  conv_wp<<<1024, 256, 0, stream>>>(wp, Wp_t);
  gemm128<0><<<dim3(64, 4, 3), 256, 0, stream>>>(query, key, value, Wq_t, Wk_t, Wv_t,
                                                 Qb, Kb, Vb, nullptr);
  attn64<<<dim3(32, 8, 4), 256, 0, stream>>>(Qb, Kb, Vb, MH);
  gemm128<1><<<dim3(64, 4, 1), 256, 0, stream>>>(MH, nullptr, nullptr, Wp_t, nullptr, nullptr,
                                                 d_out, nullptr, nullptr, bias);
}

// Round 4
// 260.674 us; speedup vs baseline: 1.1998x; 1.1998x over previous
//
#include <hip/hip_runtime.h>
#include <hip/hip_bf16.h>

// B=4, N=M=2048, D=512, H=8, HS=64, OUT=512
// conv_wqkv : W[H][D][HS] fp32 -> Wt[h*64+hs][k] bf16 (q scaled 1/8)
// conv_wp   : W[H][HS][OUT] fp32 -> Wt[out][h*64+hs] bf16
// gemm128<0>: X fp32 [8192,512] x Wt -> Q,K: [B*H][n][64] bf16; V: [B*H][hs][m] bf16 (transposed!)
// attn64    : flash attn per (b,h), 64 q-rows/block, dbuf prefetch pipeline -> MH bf16 [B][N][512]
// gemm128<1>: MH x Wp_t + bias -> out fp32 [8192,512]

typedef __attribute__((ext_vector_type(8))) short short8;
typedef __attribute__((ext_vector_type(4))) float f32x4;

#define MFMA16(a, b, c) __builtin_amdgcn_mfma_f32_16x16x32_bf16(a, b, c, 0, 0, 0)

__device__ __forceinline__ short f2bf(float f) {
  unsigned u = __builtin_bit_cast(unsigned, f);
  u += 0x7FFF + ((u >> 16) & 1);   // RNE
  return (short)(u >> 16);
}

// XOR swizzle for 128B-row LDS tiles (bases must have bits 7-9 clear).
__device__ __forceinline__ unsigned swz(unsigned byte) {
  return byte ^ (((byte >> 7) & 7) << 4);
}

// ---------------- weight conversion ----------------

__global__ void conv_wqkv(const float* __restrict__ Wq, const float* __restrict__ Wk,
                          const float* __restrict__ Wv,
                          short* __restrict__ Oq, short* __restrict__ Ok,
                          short* __restrict__ Ov) {
  int z = blockIdx.y;
  const float* W = (z == 0) ? Wq : (z == 1) ? Wk : Wv;
  short* O = (z == 0) ? Oq : (z == 1) ? Ok : Ov;
  float scale = (z == 0) ? 0.125f : 1.0f;
  int tid = blockIdx.x * 256 + threadIdx.x;
  int n = tid >> 9, k = tid & 511;
  int h = n >> 6, hs = n & 63;
  O[tid] = f2bf(W[(h * 512 + k) * 64 + hs] * scale);
}

__global__ void conv_wp(const float* __restrict__ W, short* __restrict__ O) {
  int tid = blockIdx.x * 256 + threadIdx.x;
  int n = tid >> 9, k = tid & 511;
  O[tid] = f2bf(W[k * 512 + n]);
}

// ---------------- GEMM: 128x128 tile, BK=64, dbuf + prefetch, 1 barrier/k-step ----------------
// MODE 0: A fp32 (converted on stage); z==0/1 -> [B*H][n][64] bf16, z==2 -> [B*H][hs][m] bf16
// MODE 1: A bf16; epilogue fp32 + bias

template <int MODE>
__global__ __launch_bounds__(256) void gemm128(
    const void* __restrict__ A0, const void* __restrict__ A1, const void* __restrict__ A2,
    const short* __restrict__ B0, const short* __restrict__ B1, const short* __restrict__ B2,
    void* __restrict__ O0, void* __restrict__ O1, void* __restrict__ O2,
    const float* __restrict__ bias) {
  __shared__ alignas(16) char lds[65536];  // A bufs @0,@16384; B bufs @32768,@49152
  const int z = blockIdx.z;
  const void* Ap = (z == 0) ? A0 : (z == 1) ? A1 : A2;
  const short* Bp = (z == 0) ? B0 : (z == 1) ? B1 : B2;
  void* Op = (z == 0) ? O0 : (z == 1) ? O1 : O2;

  const int tid = threadIdx.x;
  const int r0 = blockIdx.x * 128;
  const int n0 = blockIdx.y * 128;
  const int wid = tid >> 6, lane = tid & 63, g = lane >> 4, c = lane & 15;
  const int wr = wid >> 1, wc = wid & 1;
  const int srow = tid >> 3, sc8 = tid & 7;   // staging: rows srow+32*it, chunk sc8

  float4 fA[4], fB[4];
  short8 sA[4], sB[4];

  auto LOAD = [&](int ks) {
    const int k0 = ks * 64;
#pragma unroll
    for (int it = 0; it < 4; ++it) {
      int row = srow + 32 * it;
      if constexpr (MODE == 0) {
        const float* src = (const float*)Ap + (size_t)(r0 + row) * 512 + k0 + sc8 * 8;
        fA[it] = *(const float4*)(src);
        fB[it] = *(const float4*)(src + 4);
      } else {
        sA[it] = *(const short8*)((const short*)Ap + (size_t)(r0 + row) * 512 + k0 + sc8 * 8);
      }
      sB[it] = *(const short8*)(Bp + (size_t)(n0 + row) * 512 + k0 + sc8 * 8);
    }
  };
  auto WRITE = [&](int buf) {
    char* Ab = lds + buf * 16384;
    char* Bb = lds + 32768 + buf * 16384;
#pragma unroll
    for (int it = 0; it < 4; ++it) {
      int row = srow + 32 * it;
      short8 s;
      if constexpr (MODE == 0) {
        s[0] = f2bf(fA[it].x); s[1] = f2bf(fA[it].y); s[2] = f2bf(fA[it].z); s[3] = f2bf(fA[it].w);
        s[4] = f2bf(fB[it].x); s[5] = f2bf(fB[it].y); s[6] = f2bf(fB[it].z); s[7] = f2bf(fB[it].w);
      } else {
        s = sA[it];
      }
      *(short8*)(Ab + swz(row * 128 + sc8 * 16)) = s;
      *(short8*)(Bb + swz(row * 128 + sc8 * 16)) = sB[it];
    }
  };

  f32x4 acc[4][4] = {};

  LOAD(0);
  WRITE(0);
  int cur = 0;

  for (int ks = 0; ks < 8; ++ks) {
    if (ks < 7) LOAD(ks + 1);          // prefetch next k-tile (latency hides under MFMA)
    __syncthreads();                    // buf[cur] fully written by all waves
    const char* Ab = lds + cur * 16384;
    const char* Bb = lds + 32768 + cur * 16384;

    short8 af[4][2], bf[4][2];
#pragma unroll
    for (int mt = 0; mt < 4; ++mt)
#pragma unroll
      for (int kk = 0; kk < 2; ++kk) {
        int row = wr * 64 + mt * 16 + c;
        af[mt][kk] = *(const short8*)(Ab + swz(row * 128 + (g + 4 * kk) * 16));
      }
#pragma unroll
    for (int nt = 0; nt < 4; ++nt)
#pragma unroll
      for (int kk = 0; kk < 2; ++kk) {
        int nr = wc * 64 + nt * 16 + c;
        bf[nt][kk] = *(const short8*)(Bb + swz(nr * 128 + (g + 4 * kk) * 16));
      }
#pragma unroll
    for (int mt = 0; mt < 4; ++mt)
#pragma unroll
      for (int nt = 0; nt < 4; ++nt) {
        acc[mt][nt] = MFMA16(af[mt][0], bf[nt][0], acc[mt][nt]);
        acc[mt][nt] = MFMA16(af[mt][1], bf[nt][1], acc[mt][nt]);
      }

    if (ks < 7) { WRITE(cur ^ 1); cur ^= 1; }   // write next buf; other waves still read cur
  }

  // ---- epilogue ----
  if constexpr (MODE == 0) {
    short* Ob = (short*)Op;
    const bool vtrans = (z == 2);
#pragma unroll
    for (int mt = 0; mt < 4; ++mt) {
      int rowb = r0 + wr * 64 + mt * 16 + g * 4;
#pragma unroll
      for (int nt = 0; nt < 4; ++nt) {
        int col = n0 + wc * 64 + nt * 16 + c;
        int hh = col >> 6, hs = col & 63;
#pragma unroll
        for (int r = 0; r < 4; ++r) {
          int row = rowb + r;
          int bb = row >> 11, nn = row & 2047;
          size_t off = vtrans ? ((((size_t)(bb * 8 + hh)) * 64 + hs) * 2048 + nn)
                              : ((((size_t)(bb * 8 + hh)) * 2048 + nn) * 64 + hs);
          Ob[off] = f2bf(acc[mt][nt][r]);
        }
      }
    }
  } else {
    float* Of = (float*)Op;
#pragma unroll
    for (int nt = 0; nt < 4; ++nt) {
      int col = n0 + wc * 64 + nt * 16 + c;
      float bv = bias[col];
#pragma unroll
      for (int mt = 0; mt < 4; ++mt) {
        int rowb = r0 + wr * 64 + mt * 16 + g * 4;
#pragma unroll
        for (int r = 0; r < 4; ++r)
          Of[(size_t)(rowb + r) * 512 + col] = acc[mt][nt][r] + bv;
      }
    }
  }
}

// ---------------- flash attention: dbuf K/V, prefetch, 1 barrier/tile ----------------
// 256 thr = 4 waves, 16 q-rows/wave. LDS 40KB:
//   Kbuf[2] [64 kv][64 d]  @0, @8192
//   Vbuf[2] [64 hs][64 kv] @16384, @24576   (V^T tiles; Vt global layout [bh][hs][m])
//   P per wave [16 q][64 kv] @32768 + wid*2048

__global__ __launch_bounds__(256, 4) void attn64(const short* __restrict__ Qb,
                                                 const short* __restrict__ Kb,
                                                 const short* __restrict__ Vt,
                                                 short* __restrict__ MH) {
  __shared__ alignas(16) char lds[40960];
  // XCD-aware remap: all 32 q-blocks of one (b,h) land on one XCD (shared K/V in L2).
  const int flat = blockIdx.x;
  const int xcd = flat & 7, idx = flat >> 3;
  const int bh = xcd * 4 + (idx >> 5);
  const int qt = idx & 31;
  const int b = bh >> 3, h = bh & 7;

  const int tid = threadIdx.x, wid = tid >> 6, lane = tid & 63, g = lane >> 4, c = lane & 15;
  const short* Qp = Qb + ((size_t)bh * 2048 + qt * 64) * 64;
  const short* Kp = Kb + (size_t)bh * 2048 * 64;
  const short* Vp = Vt + (size_t)bh * 64 * 2048;

  const int srow = tid >> 3, sc8 = tid & 7;   // staging rows srow+32*it

  short8 qf[2];
#pragma unroll
  for (int kk = 0; kk < 2; ++kk)
    qf[kk] = *(const short8*)(Qp + (wid * 16 + c) * 64 + g * 8 + kk * 32);

  f32x4 o[4] = {};
  float mrow[4], lrow[4];
#pragma unroll
  for (int r = 0; r < 4; ++r) { mrow[r] = -1e30f; lrow[r] = 0.f; }

  const int pbase = 32768 + wid * 2048;

  short8 kr[2], vr[2];
  // prologue: tile 0
#pragma unroll
  for (int it = 0; it < 2; ++it) {
    int row = srow + it * 32;
    kr[it] = *(const short8*)(Kp + (size_t)row * 64 + sc8 * 8);
    vr[it] = *(const short8*)(Vp + (size_t)row * 2048 + sc8 * 8);
  }
#pragma unroll
  for (int it = 0; it < 2; ++it) {
    int row = srow + it * 32;
    *(short8*)(lds + swz(row * 128 + sc8 * 16)) = kr[it];
    *(short8*)(lds + 16384 + swz(row * 128 + sc8 * 16)) = vr[it];
  }
  int cur = 0;

  for (int kvt = 0; kvt < 32; ++kvt) {
    if (kvt < 31) {   // prefetch next K/V tile into regs
#pragma unroll
      for (int it = 0; it < 2; ++it) {
        int row = srow + it * 32;
        kr[it] = *(const short8*)(Kp + ((size_t)(kvt + 1) * 64 + row) * 64 + sc8 * 8);
        vr[it] = *(const short8*)(Vp + (size_t)row * 2048 + (kvt + 1) * 64 + sc8 * 8);
      }
    }
    __syncthreads();   // buf[cur] ready
    const char* Kl = lds + cur * 8192;
    const char* Vl = lds + 16384 + cur * 8192;

    // ---- S = Q K^T ----
    f32x4 s[4] = {};
#pragma unroll
    for (int t = 0; t < 4; ++t)
#pragma unroll
      for (int kk = 0; kk < 2; ++kk) {
        short8 kf = *(const short8*)(Kl + swz((t * 16 + c) * 128 + (g + 4 * kk) * 16));
        s[t] = MFMA16(qf[kk], kf, s[t]);
      }

    // ---- online softmax ----
#pragma unroll
    for (int r = 0; r < 4; ++r) {
      float vm = fmaxf(fmaxf(s[0][r], s[1][r]), fmaxf(s[2][r], s[3][r]));
      vm = fmaxf(vm, __shfl_xor(vm, 1));
      vm = fmaxf(vm, __shfl_xor(vm, 2));
      vm = fmaxf(vm, __shfl_xor(vm, 4));
      vm = fmaxf(vm, __shfl_xor(vm, 8));
      float mn = fmaxf(mrow[r], vm);
      float sc = __expf(mrow[r] - mn);
      float rs = 0.f;
#pragma unroll
      for (int t = 0; t < 4; ++t) {
        float p = __expf(s[t][r] - mn);
        s[t][r] = p;
        rs += p;
      }
      rs += __shfl_xor(rs, 1);
      rs += __shfl_xor(rs, 2);
      rs += __shfl_xor(rs, 4);
      rs += __shfl_xor(rs, 8);
      lrow[r] = lrow[r] * sc + rs;
      mrow[r] = mn;
#pragma unroll
      for (int t = 0; t < 4; ++t) o[t][r] *= sc;
    }

    // ---- P -> per-wave LDS, then PV ----
#pragma unroll
    for (int t = 0; t < 4; ++t)
#pragma unroll
      for (int r = 0; r < 4; ++r)
        *(short*)(lds + swz(pbase + (g * 4 + r) * 128 + (t * 16 + c) * 2)) = f2bf(s[t][r]);
    asm volatile("s_waitcnt lgkmcnt(0)" ::: "memory");

    short8 pa[2];
#pragma unroll
    for (int half = 0; half < 2; ++half)
      pa[half] = *(const short8*)(lds + swz(pbase + c * 128 + (g + 4 * half) * 16));
#pragma unroll
    for (int t = 0; t < 4; ++t)
#pragma unroll
      for (int half = 0; half < 2; ++half) {
        short8 vf = *(const short8*)(Vl + swz((t * 16 + c) * 128 + (g + 4 * half) * 16));
        o[t] = MFMA16(pa[half], vf, o[t]);
      }

    // ---- write next tile into other buffer ----
    if (kvt < 31) {
      char* Kn = lds + (cur ^ 1) * 8192;
      char* Vn = lds + 16384 + (cur ^ 1) * 8192;
#pragma unroll
      for (int it = 0; it < 2; ++it) {
        int row = srow + it * 32;
        *(short8*)(Kn + swz(row * 128 + sc8 * 16)) = kr[it];
        *(short8*)(Vn + swz(row * 128 + sc8 * 16)) = vr[it];
      }
      cur ^= 1;
    }
  }

  // ---- epilogue ----
#pragma unroll
  for (int t = 0; t < 4; ++t)
#pragma unroll
    for (int r = 0; r < 4; ++r) {
      float val = o[t][r] / lrow[r];
      int qrow = qt * 64 + wid * 16 + g * 4 + r;
      int col = h * 64 + t * 16 + c;
      MH[((size_t)b * 2048 + qrow) * 512 + col] = f2bf(val);
    }
}

// ---------------- launcher ----------------

extern "C" void kernel_launch(void* const* d_in, const int* in_sizes, int n_in,
                              void* d_out, int out_size, void* d_ws, size_t ws_size,
                              hipStream_t stream) {
  const float* query = (const float*)d_in[0];
  const float* key = (const float*)d_in[1];
  const float* value = (const float*)d_in[2];
  const float* wq = (const float*)d_in[3];
  const float* wk = (const float*)d_in[4];
  const float* wv = (const float*)d_in[5];
  const float* wp = (const float*)d_in[6];
  const float* bias = (const float*)d_in[7];

  char* ws = (char*)d_ws;
  short* Wq_t = (short*)(ws + 0);
  short* Wk_t = (short*)(ws + 524288);
  short* Wv_t = (short*)(ws + 1048576);
  short* Wp_t = (short*)(ws + 1572864);
  short* Qb = (short*)(ws + 2097152);
  short* Kb = (short*)(ws + 2097152 + 8388608);
  short* Vb = (short*)(ws + 2097152 + 2 * (size_t)8388608);   // Vt[bh][hs][m]
  short* MH = (short*)(ws + 2097152 + 3 * (size_t)8388608);

  conv_wqkv<<<dim3(1024, 3), 256, 0, stream>>>(wq, wk, wv, Wq_t, Wk_t, Wv_t);
  conv_wp<<<1024, 256, 0, stream>>>(wp, Wp_t);
  gemm128<0><<<dim3(64, 4, 3), 256, 0, stream>>>(query, key, value, Wq_t, Wk_t, Wv_t,
                                                 Qb, Kb, Vb, nullptr);
  attn64<<<dim3(1024), 256, 0, stream>>>(Qb, Kb, Vb, MH);
  gemm128<1><<<dim3(64, 4, 1), 256, 0, stream>>>(MH, nullptr, nullptr, Wp_t, nullptr, nullptr,
                                                 d_out, nullptr, nullptr, bias);
}